// Round 10
// baseline (338.947 us; speedup 1.0000x reference)
//
#include <hip/hip_runtime.h>
#include <hip/hip_bf16.h>

// ExpansionContrastModule on MI355X.
// ROUND 10: barrier-free k3b. Evidence: k3b ~50us (round-8 diag decomposition) vs
// ~5-8us floor; the 16-barrier/block convoy (grid 512 = 2 blocks/CU, tiny phases)
// is the only mechanism class left. Fix: v relaid channel-last v2[i][b][px][c]
// (K3a stores uint4 per 8 channels, MORE coalesced than old 4B scatters); k3b
// reads each tap's 32-channel vector directly (4x uint4 = 64B, fully-used lines,
// lane-contiguous), zero main-loop barriers, 54 independent loads/thread for MLP.
// Neighbor score rows stored NEGATED in sl so all 27 taps are pure FMA.
// Projection via wave-uniform oW s_loads. XCD y-band swizzle (512=8x64 bijective)
// keeps per-XCD v footprint ~3.3MB < 4MB L2.
// (Round-9 lesson: b128 LDS reads have an 8-pass floor; the old "8-way conflict"
// was bogus — staging was at floor; the convoy was the cost. So: remove staging.)
// k1 / K2i bodies byte-identical to round-9. Buffers: kv=d_out[0,1MB),
// srraw=ws[0,6144), v=ws[532480,25698304). 3 launches: k1 -> k23_fat -> k3b.

#define CC 32
#define HW 256
#define KVW 64

// ---------------- K1: 5x5 stride-4 pad-2 conv + bias -> kv [2,32,64,64] ----------------
__global__ __launch_bounds__(256, 2) void k1_trans(const float* __restrict__ cen,
                                                   const float* __restrict__ tW,
                                                   const float* __restrict__ tB,
                                                   float* __restrict__ kv) {
  __shared__ alignas(16) float part[4][4][64];  // [ci-quarter][co][x], 4 KB
  int bid = blockIdx.x;
  int b = bid >> 9, cog = (bid >> 6) & 7, y = bid & 63;
  int tid = threadIdx.x;
  int x = tid & 63;
  int w = __builtin_amdgcn_readfirstlane(tid >> 6);  // wave id 0..3 = ci quarter
  int ci0 = w * 8;
  int co0 = cog * 4;

  float acc[4] = {0.f, 0.f, 0.f, 0.f};
  const float4 z4 = {0.f, 0.f, 0.f, 0.f};

  int roff[5];
  bool rok[5];
#pragma unroll
  for (int r = 0; r < 5; r++) {
    int row = 4 * y - 2 + r;
    rok[r] = (row >= 0);
    roff[r] = (row < 0 ? 0 : row) * HW;
  }

  for (int cc4 = 0; cc4 < 8; cc4 += 4) {
    int ci = ci0 + cc4;
    const float* pc[4];
#pragma unroll
    for (int c = 0; c < 4; c++) pc[c] = cen + (size_t)(b * CC + ci + c) * 65536 + 4 * x;
    float4 A[4][5], B[4][5];
#pragma unroll
    for (int c = 0; c < 4; c++) {
#pragma unroll
      for (int r = 0; r < 5; r++) {
        A[c][r] = (x > 0) ? *(const float4*)(pc[c] + roff[r] - 4) : z4;
        B[c][r] = *(const float4*)(pc[c] + roff[r]);
      }
    }
#pragma unroll
    for (int r = 0; r < 5; r++) {
      if (!rok[r]) continue;  // block-uniform (only y==0, r<2)
#pragma unroll
      for (int c = 0; c < 4; c++) {
#pragma unroll
        for (int co = 0; co < 4; co++) {
          const float* wa = tW + ((co0 + co) * CC + ci + c) * 25 + r * 5;  // s_load
          acc[co] += wa[0] * A[c][r].z + wa[1] * A[c][r].w + wa[2] * B[c][r].x +
                     wa[3] * B[c][r].y + wa[4] * B[c][r].z;
        }
      }
    }
  }

#pragma unroll
  for (int co = 0; co < 4; co++) part[w][co][x] = acc[co];
  __syncthreads();
  {
    int co = tid >> 6, xx = tid & 63;
    float s = part[0][co][xx] + part[1][co][xx] + part[2][co][xx] + part[3][co][xx];
    kv[((b * CC + co0 + co) * KVW + y) * KVW + xx] = s + tB[co0 + co];
  }
}

// ---------------- K23 fat: 448 bids = 64 groups x (3 K2i + 4 K3a) interleaved --------
__device__ inline float wred64(float v) {
#pragma unroll
  for (int off = 1; off < 64; off <<= 1) v += __shfl_xor(v, off);
  return v;
}

__global__ __launch_bounds__(1024) void k23_fat(const float* __restrict__ kv,
                                                const float* __restrict__ qW,
                                                const float* __restrict__ kW,
                                                float* __restrict__ srraw,
                                                const float* __restrict__ cen,
                                                const float* __restrict__ vW,
                                                __hip_bfloat16* __restrict__ v) {
  __shared__ alignas(16) float kl[4096];  // k2i: full 64x64 k_i map (16 KB)
  __shared__ float wredl[16][18];         // k2i: per-wave D[8], M[8], Q2[16]
  int bid = blockIdx.x;
  int tid = threadIdx.x;
  int g = bid / 7, s = bid - g * 7;  // 3 K2i + 4 K3a per group of 7

  if (s < 3) {
    // ---- K2i body (verbatim round-9) ----
    int k2id = g * 3 + s;  // 0..191
    int bc = k2id / 3, i = k2id - bc * 3;
    int b = bc >> 5, c = bc & 31;
    int lane = tid & 63, w = tid >> 6;  // w 0..15
    int xx = tid & 63;
    int ybase = tid >> 6;

    float qreg[4];
#pragma unroll
    for (int r = 0; r < 4; r++) {
      int px = r * 1024 + tid;  // row = r*16 + ybase, col = xx
      float q = 0.f, kk = 0.f;
#pragma unroll
      for (int ci = 0; ci < CC; ci++) {
        float val = kv[(b * CC + ci) * 4096 + px];
        q += qW[c * CC + ci] * val;
        kk += kW[(i * CC + c) * CC + ci] * val;
      }
      qreg[r] = q;
      kl[px] = kk;
    }
    __syncthreads();

    float q2 = 0.f;
#pragma unroll
    for (int r = 0; r < 4; r++) q2 += qreg[r] * qreg[r];
    q2 = wred64(q2);
    if (lane == 0) wredl[w][16] = q2;

    constexpr int DYt[8] = {-1, -1, -1, 0, 1, 1, 1, 0};
    constexpr int DXt[8] = {-1, 0, 1, 1, 1, 0, -1, -1};
    const int d = 1 << i;
#pragma unroll
    for (int n = 0; n < 8; n++) {
      const int dy = DYt[n], dx = DXt[n];
      int xn = xx + dx * d;
      bool xok = (xn >= 0 && xn < KVW);
      float dacc = 0.f, macc = 0.f;
#pragma unroll
      for (int r = 0; r < 4; r++) {
        int yy = r * 16 + ybase;
        int px = yy * KVW + xx;
        float kc = kl[px];
        int yn = yy + dy * d;
        float kn = (xok && yn >= 0 && yn < KVW) ? kl[yn * KVW + xn] : 0.f;
        float df = kc - kn;
        dacc += qreg[r] * df;
        macc += df * df;
      }
      dacc = wred64(dacc);
      macc = wred64(macc);
      if (lane == 0) {
        wredl[w][n] = dacc;
        wredl[w][8 + n] = macc;
      }
    }
    __syncthreads();

    if (tid < 8) {
      float D = 0.f, M = 0.f, Q = 0.f;
      for (int w2 = 0; w2 < 16; w2++) {
        D += wredl[w2][tid];
        M += wredl[w2][8 + tid];
        Q += wredl[w2][16];
      }
      float sr = D / (fmaxf(sqrtf(M), 1e-12f) * fmaxf(sqrtf(Q), 1e-12f));
      srraw[bc * 24 + i * 8 + tid] = sr;
    }
  } else {
    // ---- K3a body: channel-last stores v2[i][b][px][c] (bf16) ----
    int k3id = g * 4 + (s - 3);      // 0..255
    int vb = k3id * 4 + (tid >> 8);  // virtual block 0..1023
    int b = vb >> 9, blk = vb & 511;
    int lane = tid & 63;
    int cg = __builtin_amdgcn_readfirstlane((tid >> 6) & 3);  // wave-uniform c group
    int px = blk * 128 + lane * 2;

    float2 cr[CC];
#pragma unroll
    for (int ci = 0; ci < CC; ci++)
      cr[ci] = *(const float2*)(cen + (size_t)(b * CC + ci) * 65536 + px);

    unsigned short* vo = (unsigned short*)v;
#pragma unroll
    for (int i = 0; i < 3; i++) {
      unsigned int d0[4], d1[4];  // 8 channels for px and px+1
#pragma unroll
      for (int cp = 0; cp < 4; cp++) {
        int c0 = cg * 8 + cp * 2;
        const float* wpA = vW + (i * CC + c0) * CC;  // uniform -> s_load
        const float* wpB = wpA + CC;
        float a0A = 0.f, a1A = 0.f, a0B = 0.f, a1B = 0.f;
#pragma unroll
        for (int ci = 0; ci < CC; ci++) {
          a0A += wpA[ci] * cr[ci].x;
          a1A += wpA[ci] * cr[ci].y;
          a0B += wpB[ci] * cr[ci].x;
          a1B += wpB[ci] * cr[ci].y;
        }
        __hip_bfloat16 hA0 = __float2bfloat16(a0A);
        __hip_bfloat16 hB0 = __float2bfloat16(a0B);
        __hip_bfloat16 hA1 = __float2bfloat16(a1A);
        __hip_bfloat16 hB1 = __float2bfloat16(a1B);
        d0[cp] = (unsigned int)(*(unsigned short*)&hA0) |
                 ((unsigned int)(*(unsigned short*)&hB0) << 16);
        d1[cp] = (unsigned int)(*(unsigned short*)&hA1) |
                 ((unsigned int)(*(unsigned short*)&hB1) << 16);
      }
      size_t base = ((size_t)((i * 2 + b) * 65536 + px)) * 32 + cg * 8;
      uint4 q0, q1;
      q0.x = d0[0]; q0.y = d0[1]; q0.z = d0[2]; q0.w = d0[3];
      q1.x = d1[0]; q1.y = d1[1]; q1.z = d1[2]; q1.w = d1[3];
      *(uint4*)(vo + base) = q0;        // (px,   ch cg*8..cg*8+7)
      *(uint4*)(vo + base + 32) = q1;   // (px+1, ch cg*8..cg*8+7)
    }
  }
}

// ---------------- K3b: barrier-free combine + out conv + BN + ReLU -----
__global__ __launch_bounds__(256) void k3b_combine(const __hip_bfloat16* __restrict__ v,
                                                   const float* __restrict__ srraw,
                                                   const float* __restrict__ oW,
                                                   const float* __restrict__ gamma,
                                                   const float* __restrict__ beta,
                                                   const float* __restrict__ mean,
                                                   const float* __restrict__ var,
                                                   float* __restrict__ out) {
  __shared__ alignas(16) float sl[27][32];  // 0..23: NEGATED norm scores; 24..26: +S_i
  __shared__ float bns[32], bnb[32];

  int bid0 = blockIdx.x;
  int bid = (bid0 & 7) * 64 + (bid0 >> 3);  // XCD y-band swizzle (512 = 8*64 exact)
  int b = bid >> 8, tile = bid & 255;
  int ty = tile >> 4, tx = tile & 15;
  int tid = threadIdx.x;
  int ly = tid >> 4, lx = tid & 15;
  int y = ty * 16 + ly, x = tx * 16 + lx;

  for (int f = tid; f < 768; f += 256) {
    int j = f >> 5, c = f & 31;
    sl[j][c] = srraw[(b * CC + c) * 24 + j];
  }
  if (tid < 32) {
    float inv = rsqrtf(var[tid] + 1e-5f);
    float sc = gamma[tid] * inv;
    bns[tid] = sc;
    bnb[tid] = beta[tid] - mean[tid] * sc;
  }
  __syncthreads();
  if (tid < 32) {
    float r2 = 0.f;
#pragma unroll
    for (int j = 0; j < 24; j++) {
      float s = sl[j][tid];
      r2 += s * s;
    }
    float dn = fmaxf(sqrtf(r2), 1e-12f);
#pragma unroll
    for (int i = 0; i < 3; i++) {
      float ssum = 0.f;
#pragma unroll
      for (int n = 0; n < 8; n++) {
        float sn = sl[i * 8 + n][tid] / dn;
        sl[i * 8 + n][tid] = -sn;  // negate: all taps become FMA-adds
        ssum += sn;
      }
      sl[24 + i][tid] = ssum;
    }
  }
  __syncthreads();

  constexpr int DYt[8] = {-1, -1, -1, 0, 1, 1, 1, 0};
  constexpr int DXt[8] = {-1, 0, 1, 1, 1, 0, -1, -1};

  const unsigned short* vs = (const unsigned short*)v;
  float4 pre[8];
#pragma unroll
  for (int j = 0; j < 8; j++) pre[j] = {0.f, 0.f, 0.f, 0.f};

#pragma unroll
  for (int i = 0; i < 3; i++) {
    const int d = 1 << i;
#pragma unroll
    for (int t = 0; t < 9; t++) {  // t=0 center (+S_i), t=1..8 neighbors (negated s)
      const int dy = (t == 0) ? 0 : DYt[t - 1];
      const int dx = (t == 0) ? 0 : DXt[t - 1];
      const int srow = (t == 0) ? 24 + i : i * 8 + (t - 1);
      int py = y + dy * d, px = x + dx * d;
      bool ok = (py >= 0 && py < HW && px >= 0 && px < HW);
      uint4 qa = {0u, 0u, 0u, 0u}, qb = qa, qc = qa, qd = qa;
      if (ok) {
        const unsigned short* p =
            vs + ((size_t)((i * 2 + b) * 65536 + py * HW + px)) * 32;
        qa = *(const uint4*)p;         // ch 0..7
        qb = *(const uint4*)(p + 8);   // ch 8..15
        qc = *(const uint4*)(p + 16);  // ch 16..23
        qd = *(const uint4*)(p + 24);  // ch 24..31
      }
      unsigned int dw[16] = {qa.x, qa.y, qa.z, qa.w, qb.x, qb.y, qb.z, qb.w,
                             qc.x, qc.y, qc.z, qc.w, qd.x, qd.y, qd.z, qd.w};
#pragma unroll
      for (int j = 0; j < 8; j++) {  // 4-channel chunk j = dwords 2j, 2j+1
        float4 w4 = *(const float4*)&sl[srow][j * 4];
        unsigned int u0 = dw[2 * j], u1 = dw[2 * j + 1];
        pre[j].x += w4.x * __uint_as_float(u0 << 16);
        pre[j].y += w4.y * __uint_as_float(u0 & 0xffff0000u);
        pre[j].z += w4.z * __uint_as_float(u1 << 16);
        pre[j].w += w4.w * __uint_as_float(u1 & 0xffff0000u);
      }
    }
  }

  int opx = y * HW + x;
#pragma unroll
  for (int co = 0; co < CC; co++) {
    const float* owr = oW + co * CC;  // uniform -> s_load
    float s = 0.f;
#pragma unroll
    for (int j = 0; j < 8; j++) {
      float4 w = *(const float4*)(owr + j * 4);
      s += w.x * pre[j].x + w.y * pre[j].y + w.z * pre[j].z + w.w * pre[j].w;
    }
    float val = s * bns[co] + bnb[co];
    out[((size_t)(b * CC + co) << 16) + opx] = fmaxf(val, 0.f);
  }
}

extern "C" void kernel_launch(void* const* d_in, const int* in_sizes, int n_in,
                              void* d_out, int out_size, void* d_ws, size_t ws_size,
                              hipStream_t stream) {
  const float* cen = (const float*)d_in[0];
  const float* trans_W = (const float*)d_in[1];
  const float* trans_b = (const float*)d_in[2];
  const float* query_W = (const float*)d_in[3];
  const float* value_W = (const float*)d_in[4];
  const float* key_W = (const float*)d_in[5];
  const float* out_W = (const float*)d_in[6];
  const float* bn_gamma = (const float*)d_in[7];
  const float* bn_beta = (const float*)d_in[8];
  const float* bn_mean = (const float*)d_in[9];
  const float* bn_var = (const float*)d_in[10];
  float* out = (float*)d_out;

  // Buffer plan (race-free, round-7 proven):
  //   kv    = d_out[0, 1048576)    -- fp32 scratch; fully overwritten by k3b.
  //   srraw = ws[0, 6144)
  //   v     = ws[532480, 25698304) -- bf16, channel-last [3][2][65536][32]
  float* kv = (float*)d_out;
  float* srraw = (float*)d_ws;
  __hip_bfloat16* v = (__hip_bfloat16*)((char*)d_ws + 532480);

  k1_trans<<<1024, 256, 0, stream>>>(cen, trans_W, trans_b, kv);
  k23_fat<<<448, 1024, 0, stream>>>(kv, query_W, key_W, srraw, cen, value_W, v);
  k3b_combine<<<512, 256, 0, stream>>>(v, srraw, out_W, bn_gamma, bn_beta, bn_mean,
                                       bn_var, out);
}

// Round 12
// 251.035 us; speedup vs baseline: 1.3502x; 1.3502x over previous
//
#include <hip/hip_runtime.h>
#include <hip/hip_bf16.h>

// ExpansionContrastModule on MI355X.
// ROUND 12 (= round-11 resubmit; round 11 was a GPU-acquisition timeout, never ran).
// Fix round-10's k3b register spill (VGPR=256, 408MB scratch WRITES —
// 27 taps x 16 dwords unrolled = 432 VGPRs of in-flight loads). Keep the
// barrier-free channel-last structure but chunk channels 8-at-a-time:
// cg loop (#pragma unroll 1), per tap ONE uint4 (4 VGPR), projection folded
// into each cg chunk (same j-order as round-10 => identical numerics).
// Live set ~ sacc[32]+pre[8]+9 taps ~ 110 VGPR -> no spill. v re-read 4x from
// L2 (226MB chip-wide ~ 7us at L2 BW). k1 + k23_fat byte-identical to round 10
// (channel-last K3a proven there). Buffers: kv=d_out[0,1MB), srraw=ws[0,6144),
// v=ws[532480,25698304) channel-last [3][2][65536][32] bf16.

#define CC 32
#define HW 256
#define KVW 64

// ---------------- K1: 5x5 stride-4 pad-2 conv + bias -> kv [2,32,64,64] ----------------
__global__ __launch_bounds__(256, 2) void k1_trans(const float* __restrict__ cen,
                                                   const float* __restrict__ tW,
                                                   const float* __restrict__ tB,
                                                   float* __restrict__ kv) {
  __shared__ alignas(16) float part[4][4][64];  // [ci-quarter][co][x], 4 KB
  int bid = blockIdx.x;
  int b = bid >> 9, cog = (bid >> 6) & 7, y = bid & 63;
  int tid = threadIdx.x;
  int x = tid & 63;
  int w = __builtin_amdgcn_readfirstlane(tid >> 6);  // wave id 0..3 = ci quarter
  int ci0 = w * 8;
  int co0 = cog * 4;

  float acc[4] = {0.f, 0.f, 0.f, 0.f};
  const float4 z4 = {0.f, 0.f, 0.f, 0.f};

  int roff[5];
  bool rok[5];
#pragma unroll
  for (int r = 0; r < 5; r++) {
    int row = 4 * y - 2 + r;
    rok[r] = (row >= 0);
    roff[r] = (row < 0 ? 0 : row) * HW;
  }

  for (int cc4 = 0; cc4 < 8; cc4 += 4) {
    int ci = ci0 + cc4;
    const float* pc[4];
#pragma unroll
    for (int c = 0; c < 4; c++) pc[c] = cen + (size_t)(b * CC + ci + c) * 65536 + 4 * x;
    float4 A[4][5], B[4][5];
#pragma unroll
    for (int c = 0; c < 4; c++) {
#pragma unroll
      for (int r = 0; r < 5; r++) {
        A[c][r] = (x > 0) ? *(const float4*)(pc[c] + roff[r] - 4) : z4;
        B[c][r] = *(const float4*)(pc[c] + roff[r]);
      }
    }
#pragma unroll
    for (int r = 0; r < 5; r++) {
      if (!rok[r]) continue;  // block-uniform (only y==0, r<2)
#pragma unroll
      for (int c = 0; c < 4; c++) {
#pragma unroll
        for (int co = 0; co < 4; co++) {
          const float* wa = tW + ((co0 + co) * CC + ci + c) * 25 + r * 5;  // s_load
          acc[co] += wa[0] * A[c][r].z + wa[1] * A[c][r].w + wa[2] * B[c][r].x +
                     wa[3] * B[c][r].y + wa[4] * B[c][r].z;
        }
      }
    }
  }

#pragma unroll
  for (int co = 0; co < 4; co++) part[w][co][x] = acc[co];
  __syncthreads();
  {
    int co = tid >> 6, xx = tid & 63;
    float s = part[0][co][xx] + part[1][co][xx] + part[2][co][xx] + part[3][co][xx];
    kv[((b * CC + co0 + co) * KVW + y) * KVW + xx] = s + tB[co0 + co];
  }
}

// ---------------- K23 fat: 448 bids = 64 groups x (3 K2i + 4 K3a) interleaved --------
__device__ inline float wred64(float v) {
#pragma unroll
  for (int off = 1; off < 64; off <<= 1) v += __shfl_xor(v, off);
  return v;
}

__global__ __launch_bounds__(1024) void k23_fat(const float* __restrict__ kv,
                                                const float* __restrict__ qW,
                                                const float* __restrict__ kW,
                                                float* __restrict__ srraw,
                                                const float* __restrict__ cen,
                                                const float* __restrict__ vW,
                                                __hip_bfloat16* __restrict__ v) {
  __shared__ alignas(16) float kl[4096];  // k2i: full 64x64 k_i map (16 KB)
  __shared__ float wredl[16][18];         // k2i: per-wave D[8], M[8], Q2[16]
  int bid = blockIdx.x;
  int tid = threadIdx.x;
  int g = bid / 7, s = bid - g * 7;  // 3 K2i + 4 K3a per group of 7

  if (s < 3) {
    // ---- K2i body (verbatim) ----
    int k2id = g * 3 + s;  // 0..191
    int bc = k2id / 3, i = k2id - bc * 3;
    int b = bc >> 5, c = bc & 31;
    int lane = tid & 63, w = tid >> 6;  // w 0..15
    int xx = tid & 63;
    int ybase = tid >> 6;

    float qreg[4];
#pragma unroll
    for (int r = 0; r < 4; r++) {
      int px = r * 1024 + tid;  // row = r*16 + ybase, col = xx
      float q = 0.f, kk = 0.f;
#pragma unroll
      for (int ci = 0; ci < CC; ci++) {
        float val = kv[(b * CC + ci) * 4096 + px];
        q += qW[c * CC + ci] * val;
        kk += kW[(i * CC + c) * CC + ci] * val;
      }
      qreg[r] = q;
      kl[px] = kk;
    }
    __syncthreads();

    float q2 = 0.f;
#pragma unroll
    for (int r = 0; r < 4; r++) q2 += qreg[r] * qreg[r];
    q2 = wred64(q2);
    if (lane == 0) wredl[w][16] = q2;

    constexpr int DYt[8] = {-1, -1, -1, 0, 1, 1, 1, 0};
    constexpr int DXt[8] = {-1, 0, 1, 1, 1, 0, -1, -1};
    const int d = 1 << i;
#pragma unroll
    for (int n = 0; n < 8; n++) {
      const int dy = DYt[n], dx = DXt[n];
      int xn = xx + dx * d;
      bool xok = (xn >= 0 && xn < KVW);
      float dacc = 0.f, macc = 0.f;
#pragma unroll
      for (int r = 0; r < 4; r++) {
        int yy = r * 16 + ybase;
        int px = yy * KVW + xx;
        float kc = kl[px];
        int yn = yy + dy * d;
        float kn = (xok && yn >= 0 && yn < KVW) ? kl[yn * KVW + xn] : 0.f;
        float df = kc - kn;
        dacc += qreg[r] * df;
        macc += df * df;
      }
      dacc = wred64(dacc);
      macc = wred64(macc);
      if (lane == 0) {
        wredl[w][n] = dacc;
        wredl[w][8 + n] = macc;
      }
    }
    __syncthreads();

    if (tid < 8) {
      float D = 0.f, M = 0.f, Q = 0.f;
      for (int w2 = 0; w2 < 16; w2++) {
        D += wredl[w2][tid];
        M += wredl[w2][8 + tid];
        Q += wredl[w2][16];
      }
      float sr = D / (fmaxf(sqrtf(M), 1e-12f) * fmaxf(sqrtf(Q), 1e-12f));
      srraw[bc * 24 + i * 8 + tid] = sr;
    }
  } else {
    // ---- K3a body: channel-last stores v2[i][b][px][c] (bf16), verbatim ----
    int k3id = g * 4 + (s - 3);      // 0..255
    int vb = k3id * 4 + (tid >> 8);  // virtual block 0..1023
    int b = vb >> 9, blk = vb & 511;
    int lane = tid & 63;
    int cg = __builtin_amdgcn_readfirstlane((tid >> 6) & 3);  // wave-uniform c group
    int px = blk * 128 + lane * 2;

    float2 cr[CC];
#pragma unroll
    for (int ci = 0; ci < CC; ci++)
      cr[ci] = *(const float2*)(cen + (size_t)(b * CC + ci) * 65536 + px);

    unsigned short* vo = (unsigned short*)v;
#pragma unroll
    for (int i = 0; i < 3; i++) {
      unsigned int d0[4], d1[4];  // 8 channels for px and px+1
#pragma unroll
      for (int cp = 0; cp < 4; cp++) {
        int c0 = cg * 8 + cp * 2;
        const float* wpA = vW + (i * CC + c0) * CC;  // uniform -> s_load
        const float* wpB = wpA + CC;
        float a0A = 0.f, a1A = 0.f, a0B = 0.f, a1B = 0.f;
#pragma unroll
        for (int ci = 0; ci < CC; ci++) {
          a0A += wpA[ci] * cr[ci].x;
          a1A += wpA[ci] * cr[ci].y;
          a0B += wpB[ci] * cr[ci].x;
          a1B += wpB[ci] * cr[ci].y;
        }
        __hip_bfloat16 hA0 = __float2bfloat16(a0A);
        __hip_bfloat16 hB0 = __float2bfloat16(a0B);
        __hip_bfloat16 hA1 = __float2bfloat16(a1A);
        __hip_bfloat16 hB1 = __float2bfloat16(a1B);
        d0[cp] = (unsigned int)(*(unsigned short*)&hA0) |
                 ((unsigned int)(*(unsigned short*)&hB0) << 16);
        d1[cp] = (unsigned int)(*(unsigned short*)&hA1) |
                 ((unsigned int)(*(unsigned short*)&hB1) << 16);
      }
      size_t base = ((size_t)((i * 2 + b) * 65536 + px)) * 32 + cg * 8;
      uint4 q0, q1;
      q0.x = d0[0]; q0.y = d0[1]; q0.z = d0[2]; q0.w = d0[3];
      q1.x = d1[0]; q1.y = d1[1]; q1.z = d1[2]; q1.w = d1[3];
      *(uint4*)(vo + base) = q0;        // (px,   ch cg*8..cg*8+7)
      *(uint4*)(vo + base + 32) = q1;   // (px+1, ch cg*8..cg*8+7)
    }
  }
}

// ---------------- K3b: barrier-free, cg-chunked (8 ch/iter) combine + conv + BN + ReLU -
__global__ __launch_bounds__(256, 2) void k3b_combine(
    const __hip_bfloat16* __restrict__ v, const float* __restrict__ srraw,
    const float* __restrict__ oW, const float* __restrict__ gamma,
    const float* __restrict__ beta, const float* __restrict__ mean,
    const float* __restrict__ var, float* __restrict__ out) {
  __shared__ alignas(16) float sl[27][32];  // 0..23: NEGATED norm scores; 24..26: +S_i
  __shared__ float bns[32], bnb[32];

  int bid0 = blockIdx.x;
  int bid = (bid0 & 7) * 64 + (bid0 >> 3);  // XCD y-band swizzle (512 = 8*64 exact)
  int b = bid >> 8, tile = bid & 255;
  int ty = tile >> 4, tx = tile & 15;
  int tid = threadIdx.x;
  int ly = tid >> 4, lx = tid & 15;
  int y = ty * 16 + ly, x = tx * 16 + lx;

  for (int f = tid; f < 768; f += 256) {
    int j = f >> 5, c = f & 31;
    sl[j][c] = srraw[(b * CC + c) * 24 + j];
  }
  if (tid < 32) {
    float inv = rsqrtf(var[tid] + 1e-5f);
    float sc = gamma[tid] * inv;
    bns[tid] = sc;
    bnb[tid] = beta[tid] - mean[tid] * sc;
  }
  __syncthreads();
  if (tid < 32) {
    float r2 = 0.f;
#pragma unroll
    for (int j = 0; j < 24; j++) {
      float s = sl[j][tid];
      r2 += s * s;
    }
    float dn = fmaxf(sqrtf(r2), 1e-12f);
#pragma unroll
    for (int i = 0; i < 3; i++) {
      float ssum = 0.f;
#pragma unroll
      for (int n = 0; n < 8; n++) {
        float sn = sl[i * 8 + n][tid] / dn;
        sl[i * 8 + n][tid] = -sn;  // negate: all taps become FMA-adds
        ssum += sn;
      }
      sl[24 + i][tid] = ssum;
    }
  }
  __syncthreads();

  constexpr int DYt[8] = {-1, -1, -1, 0, 1, 1, 1, 0};
  constexpr int DXt[8] = {-1, 0, 1, 1, 1, 0, -1, -1};

  const unsigned short* vs = (const unsigned short*)v;
  float sacc[32];
#pragma unroll
  for (int co = 0; co < CC; co++) sacc[co] = 0.f;

#pragma unroll 1
  for (int cg = 0; cg < 4; cg++) {  // 8 channels per iteration -> low VGPR pressure
    float4 preA = {0.f, 0.f, 0.f, 0.f};  // ch cg*8 .. cg*8+3
    float4 preB = {0.f, 0.f, 0.f, 0.f};  // ch cg*8+4 .. cg*8+7
#pragma unroll
    for (int i = 0; i < 3; i++) {
      const int d = 1 << i;
#pragma unroll
      for (int t = 0; t < 9; t++) {  // t=0 center (+S_i), t=1..8 neighbors (negated)
        const int dy = (t == 0) ? 0 : DYt[t - 1];
        const int dx = (t == 0) ? 0 : DXt[t - 1];
        const int srow = (t == 0) ? 24 + i : i * 8 + (t - 1);
        int py = y + dy * d, px = x + dx * d;
        bool ok = (py >= 0 && py < HW && px >= 0 && px < HW);
        uint4 q = {0u, 0u, 0u, 0u};
        if (ok)
          q = *(const uint4*)(vs +
                              ((size_t)((i * 2 + b) * 65536 + py * HW + px)) * 32 +
                              cg * 8);
        float4 wA = *(const float4*)&sl[srow][cg * 8];
        float4 wB = *(const float4*)&sl[srow][cg * 8 + 4];
        preA.x += wA.x * __uint_as_float(q.x << 16);
        preA.y += wA.y * __uint_as_float(q.x & 0xffff0000u);
        preA.z += wA.z * __uint_as_float(q.y << 16);
        preA.w += wA.w * __uint_as_float(q.y & 0xffff0000u);
        preB.x += wB.x * __uint_as_float(q.z << 16);
        preB.y += wB.y * __uint_as_float(q.z & 0xffff0000u);
        preB.z += wB.z * __uint_as_float(q.w << 16);
        preB.w += wB.w * __uint_as_float(q.w & 0xffff0000u);
      }
    }
    // projection partial for this 8-channel chunk (j order = round-10's j=2cg, 2cg+1)
#pragma unroll
    for (int co = 0; co < CC; co++) {
      const float* owr = oW + co * CC + cg * 8;  // uniform -> s_load
      float4 oA = *(const float4*)owr;
      float4 oB = *(const float4*)(owr + 4);
      sacc[co] += oA.x * preA.x + oA.y * preA.y + oA.z * preA.z + oA.w * preA.w +
                  oB.x * preB.x + oB.y * preB.y + oB.z * preB.z + oB.w * preB.w;
    }
  }

  int opx = y * HW + x;
#pragma unroll
  for (int co = 0; co < CC; co++) {
    float val = sacc[co] * bns[co] + bnb[co];
    out[((size_t)(b * CC + co) << 16) + opx] = fmaxf(val, 0.f);
  }
}

extern "C" void kernel_launch(void* const* d_in, const int* in_sizes, int n_in,
                              void* d_out, int out_size, void* d_ws, size_t ws_size,
                              hipStream_t stream) {
  const float* cen = (const float*)d_in[0];
  const float* trans_W = (const float*)d_in[1];
  const float* trans_b = (const float*)d_in[2];
  const float* query_W = (const float*)d_in[3];
  const float* value_W = (const float*)d_in[4];
  const float* key_W = (const float*)d_in[5];
  const float* out_W = (const float*)d_in[6];
  const float* bn_gamma = (const float*)d_in[7];
  const float* bn_beta = (const float*)d_in[8];
  const float* bn_mean = (const float*)d_in[9];
  const float* bn_var = (const float*)d_in[10];
  float* out = (float*)d_out;

  // Buffer plan (race-free, round-7 proven):
  //   kv    = d_out[0, 1048576)    -- fp32 scratch; fully overwritten by k3b.
  //   srraw = ws[0, 6144)
  //   v     = ws[532480, 25698304) -- bf16, channel-last [3][2][65536][32]
  float* kv = (float*)d_out;
  float* srraw = (float*)d_ws;
  __hip_bfloat16* v = (__hip_bfloat16*)((char*)d_ws + 532480);

  k1_trans<<<1024, 256, 0, stream>>>(cen, trans_W, trans_b, kv);
  k23_fat<<<448, 1024, 0, stream>>>(kv, query_W, key_W, srraw, cen, value_W, v);
  k3b_combine<<<512, 256, 0, stream>>>(v, srraw, out_W, bn_gamma, bn_beta, bn_mean,
                                       bn_var, out);
}

// Round 19
// 196.689 us; speedup vs baseline: 1.7233x; 1.2763x over previous
//
#include <hip/hip_runtime.h>
#include <hip/hip_bf16.h>

// ExpansionContrastModule on MI355X.
// ROUND 19 (= round-13..18 resubmit; six consecutive GPU-acquisition timeouts).
// Kill k3b's spill BY CONSTRUCTION. Round-12 counters: VGPR pinned at
// 128 cap, WRITE 267MB / FETCH 214MB = sacc[32] spilled in the cg loop (scratch
// round-trips), dur 128-170us. Per-thread-32-channel mixing + 27-tap streaming
// can't fit registers. New k3b: block = 64 px (8x8 tile) x 4 channel-quarters.
// Phase A: thread (px,cq) gathers ONLY its 8-ch chunk per tap (uint4), makes
// pre[8] (live ~40 VGPR), stores to LDS pre[64][36] (conflict-free). Phase B
// (1 barrier): thread computes 8 output channels from LDS pre in cg order —
// identical FP order to round-12 (passed) => numerics preserved. 3 barriers
// total, grid 2048 (8 blk/CU, ~13KB LDS), 8x8 tiles for tap overlap, XCD
// swizzle 2048=8x256 exact. k1 + k23_fat byte-identical to round-12 (passed 2x).
// Buffers: kv=d_out[0,1MB), srraw=ws[0,6144), v=ws[532480,...) channel-last.

#define CC 32
#define HW 256
#define KVW 64

// ---------------- K1: 5x5 stride-4 pad-2 conv + bias -> kv [2,32,64,64] ----------------
__global__ __launch_bounds__(256, 2) void k1_trans(const float* __restrict__ cen,
                                                   const float* __restrict__ tW,
                                                   const float* __restrict__ tB,
                                                   float* __restrict__ kv) {
  __shared__ alignas(16) float part[4][4][64];  // [ci-quarter][co][x], 4 KB
  int bid = blockIdx.x;
  int b = bid >> 9, cog = (bid >> 6) & 7, y = bid & 63;
  int tid = threadIdx.x;
  int x = tid & 63;
  int w = __builtin_amdgcn_readfirstlane(tid >> 6);  // wave id 0..3 = ci quarter
  int ci0 = w * 8;
  int co0 = cog * 4;

  float acc[4] = {0.f, 0.f, 0.f, 0.f};
  const float4 z4 = {0.f, 0.f, 0.f, 0.f};

  int roff[5];
  bool rok[5];
#pragma unroll
  for (int r = 0; r < 5; r++) {
    int row = 4 * y - 2 + r;
    rok[r] = (row >= 0);
    roff[r] = (row < 0 ? 0 : row) * HW;
  }

  for (int cc4 = 0; cc4 < 8; cc4 += 4) {
    int ci = ci0 + cc4;
    const float* pc[4];
#pragma unroll
    for (int c = 0; c < 4; c++) pc[c] = cen + (size_t)(b * CC + ci + c) * 65536 + 4 * x;
    float4 A[4][5], B[4][5];
#pragma unroll
    for (int c = 0; c < 4; c++) {
#pragma unroll
      for (int r = 0; r < 5; r++) {
        A[c][r] = (x > 0) ? *(const float4*)(pc[c] + roff[r] - 4) : z4;
        B[c][r] = *(const float4*)(pc[c] + roff[r]);
      }
    }
#pragma unroll
    for (int r = 0; r < 5; r++) {
      if (!rok[r]) continue;  // block-uniform (only y==0, r<2)
#pragma unroll
      for (int c = 0; c < 4; c++) {
#pragma unroll
        for (int co = 0; co < 4; co++) {
          const float* wa = tW + ((co0 + co) * CC + ci + c) * 25 + r * 5;  // s_load
          acc[co] += wa[0] * A[c][r].z + wa[1] * A[c][r].w + wa[2] * B[c][r].x +
                     wa[3] * B[c][r].y + wa[4] * B[c][r].z;
        }
      }
    }
  }

#pragma unroll
  for (int co = 0; co < 4; co++) part[w][co][x] = acc[co];
  __syncthreads();
  {
    int co = tid >> 6, xx = tid & 63;
    float s = part[0][co][xx] + part[1][co][xx] + part[2][co][xx] + part[3][co][xx];
    kv[((b * CC + co0 + co) * KVW + y) * KVW + xx] = s + tB[co0 + co];
  }
}

// ---------------- K23 fat: 448 bids = 64 groups x (3 K2i + 4 K3a) interleaved --------
__device__ inline float wred64(float v) {
#pragma unroll
  for (int off = 1; off < 64; off <<= 1) v += __shfl_xor(v, off);
  return v;
}

__global__ __launch_bounds__(1024) void k23_fat(const float* __restrict__ kv,
                                                const float* __restrict__ qW,
                                                const float* __restrict__ kW,
                                                float* __restrict__ srraw,
                                                const float* __restrict__ cen,
                                                const float* __restrict__ vW,
                                                __hip_bfloat16* __restrict__ v) {
  __shared__ alignas(16) float kl[4096];  // k2i: full 64x64 k_i map (16 KB)
  __shared__ float wredl[16][18];         // k2i: per-wave D[8], M[8], Q2[16]
  int bid = blockIdx.x;
  int tid = threadIdx.x;
  int g = bid / 7, s = bid - g * 7;  // 3 K2i + 4 K3a per group of 7

  if (s < 3) {
    // ---- K2i body (verbatim) ----
    int k2id = g * 3 + s;  // 0..191
    int bc = k2id / 3, i = k2id - bc * 3;
    int b = bc >> 5, c = bc & 31;
    int lane = tid & 63, w = tid >> 6;  // w 0..15
    int xx = tid & 63;
    int ybase = tid >> 6;

    float qreg[4];
#pragma unroll
    for (int r = 0; r < 4; r++) {
      int px = r * 1024 + tid;  // row = r*16 + ybase, col = xx
      float q = 0.f, kk = 0.f;
#pragma unroll
      for (int ci = 0; ci < CC; ci++) {
        float val = kv[(b * CC + ci) * 4096 + px];
        q += qW[c * CC + ci] * val;
        kk += kW[(i * CC + c) * CC + ci] * val;
      }
      qreg[r] = q;
      kl[px] = kk;
    }
    __syncthreads();

    float q2 = 0.f;
#pragma unroll
    for (int r = 0; r < 4; r++) q2 += qreg[r] * qreg[r];
    q2 = wred64(q2);
    if (lane == 0) wredl[w][16] = q2;

    constexpr int DYt[8] = {-1, -1, -1, 0, 1, 1, 1, 0};
    constexpr int DXt[8] = {-1, 0, 1, 1, 1, 0, -1, -1};
    const int d = 1 << i;
#pragma unroll
    for (int n = 0; n < 8; n++) {
      const int dy = DYt[n], dx = DXt[n];
      int xn = xx + dx * d;
      bool xok = (xn >= 0 && xn < KVW);
      float dacc = 0.f, macc = 0.f;
#pragma unroll
      for (int r = 0; r < 4; r++) {
        int yy = r * 16 + ybase;
        int px = yy * KVW + xx;
        float kc = kl[px];
        int yn = yy + dy * d;
        float kn = (xok && yn >= 0 && yn < KVW) ? kl[yn * KVW + xn] : 0.f;
        float df = kc - kn;
        dacc += qreg[r] * df;
        macc += df * df;
      }
      dacc = wred64(dacc);
      macc = wred64(macc);
      if (lane == 0) {
        wredl[w][n] = dacc;
        wredl[w][8 + n] = macc;
      }
    }
    __syncthreads();

    if (tid < 8) {
      float D = 0.f, M = 0.f, Q = 0.f;
      for (int w2 = 0; w2 < 16; w2++) {
        D += wredl[w2][tid];
        M += wredl[w2][8 + tid];
        Q += wredl[w2][16];
      }
      float sr = D / (fmaxf(sqrtf(M), 1e-12f) * fmaxf(sqrtf(Q), 1e-12f));
      srraw[bc * 24 + i * 8 + tid] = sr;
    }
  } else {
    // ---- K3a body: channel-last stores v2[i][b][px][c] (bf16), verbatim ----
    int k3id = g * 4 + (s - 3);      // 0..255
    int vb = k3id * 4 + (tid >> 8);  // virtual block 0..1023
    int b = vb >> 9, blk = vb & 511;
    int lane = tid & 63;
    int cg = __builtin_amdgcn_readfirstlane((tid >> 6) & 3);  // wave-uniform c group
    int px = blk * 128 + lane * 2;

    float2 cr[CC];
#pragma unroll
    for (int ci = 0; ci < CC; ci++)
      cr[ci] = *(const float2*)(cen + (size_t)(b * CC + ci) * 65536 + px);

    unsigned short* vo = (unsigned short*)v;
#pragma unroll
    for (int i = 0; i < 3; i++) {
      unsigned int d0[4], d1[4];  // 8 channels for px and px+1
#pragma unroll
      for (int cp = 0; cp < 4; cp++) {
        int c0 = cg * 8 + cp * 2;
        const float* wpA = vW + (i * CC + c0) * CC;  // uniform -> s_load
        const float* wpB = wpA + CC;
        float a0A = 0.f, a1A = 0.f, a0B = 0.f, a1B = 0.f;
#pragma unroll
        for (int ci = 0; ci < CC; ci++) {
          a0A += wpA[ci] * cr[ci].x;
          a1A += wpA[ci] * cr[ci].y;
          a0B += wpB[ci] * cr[ci].x;
          a1B += wpB[ci] * cr[ci].y;
        }
        __hip_bfloat16 hA0 = __float2bfloat16(a0A);
        __hip_bfloat16 hB0 = __float2bfloat16(a0B);
        __hip_bfloat16 hA1 = __float2bfloat16(a1A);
        __hip_bfloat16 hB1 = __float2bfloat16(a1B);
        d0[cp] = (unsigned int)(*(unsigned short*)&hA0) |
                 ((unsigned int)(*(unsigned short*)&hB0) << 16);
        d1[cp] = (unsigned int)(*(unsigned short*)&hA1) |
                 ((unsigned int)(*(unsigned short*)&hB1) << 16);
      }
      size_t base = ((size_t)((i * 2 + b) * 65536 + px)) * 32 + cg * 8;
      uint4 q0, q1;
      q0.x = d0[0]; q0.y = d0[1]; q0.z = d0[2]; q0.w = d0[3];
      q1.x = d1[0]; q1.y = d1[1]; q1.z = d1[2]; q1.w = d1[3];
      *(uint4*)(vo + base) = q0;        // (px,   ch cg*8..cg*8+7)
      *(uint4*)(vo + base + 32) = q1;   // (px+1, ch cg*8..cg*8+7)
    }
  }
}

// ---------------- K3b: 64px x 4 channel-quarters, LDS pre exchange ----------
#define PRS 36  // pre row stride (floats); 36%32=4 -> conflict-free float4 phases
__global__ __launch_bounds__(256, 2) void k3b_combine(
    const __hip_bfloat16* __restrict__ v, const float* __restrict__ srraw,
    const float* __restrict__ oW, const float* __restrict__ gamma,
    const float* __restrict__ beta, const float* __restrict__ mean,
    const float* __restrict__ var, float* __restrict__ out) {
  __shared__ alignas(16) float sl[27][32];  // 0..23: NEGATED norm scores; 24..26: +S_i
  __shared__ alignas(16) float pre[64 * PRS];  // [px][36] combined tap vectors, 9.2 KB
  __shared__ float bns[32], bnb[32];

  int bid0 = blockIdx.x;
  int bid = (bid0 & 7) * 256 + (bid0 >> 3);  // XCD swizzle (2048 = 8*256 exact)
  int b = bid >> 10;
  int t6 = bid & 1023;               // 32x32 grid of 8x8 tiles
  int ty = t6 >> 5, tx = t6 & 31;
  int tid = threadIdx.x;
  int pxl = tid & 63;                                       // local pixel 0..63
  int cq = __builtin_amdgcn_readfirstlane(tid >> 6);        // channel quarter 0..3
  int y = ty * 8 + (pxl >> 3), x = tx * 8 + (pxl & 7);

  for (int f = tid; f < 768; f += 256) {
    int j = f >> 5, c = f & 31;
    sl[j][c] = srraw[(b * CC + c) * 24 + j];
  }
  if (tid < 32) {
    float inv = rsqrtf(var[tid] + 1e-5f);
    float sc = gamma[tid] * inv;
    bns[tid] = sc;
    bnb[tid] = beta[tid] - mean[tid] * sc;
  }
  __syncthreads();
  if (tid < 32) {
    float r2 = 0.f;
#pragma unroll
    for (int j = 0; j < 24; j++) {
      float s = sl[j][tid];
      r2 += s * s;
    }
    float dn = fmaxf(sqrtf(r2), 1e-12f);
#pragma unroll
    for (int i = 0; i < 3; i++) {
      float ssum = 0.f;
#pragma unroll
      for (int n = 0; n < 8; n++) {
        float sn = sl[i * 8 + n][tid] / dn;
        sl[i * 8 + n][tid] = -sn;  // negate: all taps become FMA-adds
        ssum += sn;
      }
      sl[24 + i][tid] = ssum;
    }
  }
  __syncthreads();

  constexpr int DYt[8] = {-1, -1, -1, 0, 1, 1, 1, 0};
  constexpr int DXt[8] = {-1, 0, 1, 1, 1, 0, -1, -1};

  // ---- Phase A: gather this thread's 8-channel chunk over 27 taps ----
  const unsigned short* vs = (const unsigned short*)v;
  float4 preA = {0.f, 0.f, 0.f, 0.f};  // ch cq*8 .. cq*8+3
  float4 preB = {0.f, 0.f, 0.f, 0.f};  // ch cq*8+4 .. cq*8+7
#pragma unroll
  for (int i = 0; i < 3; i++) {
    const int d = 1 << i;
#pragma unroll
    for (int t = 0; t < 9; t++) {  // t=0 center (+S_i), t=1..8 neighbors (negated)
      const int dy = (t == 0) ? 0 : DYt[t - 1];
      const int dx = (t == 0) ? 0 : DXt[t - 1];
      const int srow = (t == 0) ? 24 + i : i * 8 + (t - 1);
      int py = y + dy * d, px = x + dx * d;
      bool ok = (py >= 0 && py < HW && px >= 0 && px < HW);
      uint4 q = {0u, 0u, 0u, 0u};
      if (ok)
        q = *(const uint4*)(vs + ((size_t)((i * 2 + b) * 65536 + py * HW + px)) * 32 +
                            cq * 8);
      float4 wA = *(const float4*)&sl[srow][cq * 8];
      float4 wB = *(const float4*)&sl[srow][cq * 8 + 4];
      preA.x += wA.x * __uint_as_float(q.x << 16);
      preA.y += wA.y * __uint_as_float(q.x & 0xffff0000u);
      preA.z += wA.z * __uint_as_float(q.y << 16);
      preA.w += wA.w * __uint_as_float(q.y & 0xffff0000u);
      preB.x += wB.x * __uint_as_float(q.z << 16);
      preB.y += wB.y * __uint_as_float(q.z & 0xffff0000u);
      preB.z += wB.z * __uint_as_float(q.w << 16);
      preB.w += wB.w * __uint_as_float(q.w & 0xffff0000u);
    }
  }
  *(float4*)&pre[pxl * PRS + cq * 8] = preA;
  *(float4*)&pre[pxl * PRS + cq * 8 + 4] = preB;
  __syncthreads();

  // ---- Phase B: this thread's 8 output channels from LDS pre (cg order = round-12) --
  float sacc[8];
#pragma unroll
  for (int co = 0; co < 8; co++) sacc[co] = 0.f;
#pragma unroll
  for (int cg = 0; cg < 4; cg++) {
    float4 pA = *(const float4*)&pre[pxl * PRS + cg * 8];
    float4 pB = *(const float4*)&pre[pxl * PRS + cg * 8 + 4];
#pragma unroll
    for (int co = 0; co < 8; co++) {
      const float* owr = oW + (cq * 8 + co) * CC + cg * 8;  // uniform -> s_load
      float4 oA = *(const float4*)owr;
      float4 oB = *(const float4*)(owr + 4);
      sacc[co] += oA.x * pA.x + oA.y * pA.y + oA.z * pA.z + oA.w * pA.w +
                  oB.x * pB.x + oB.y * pB.y + oB.z * pB.z + oB.w * pB.w;
    }
  }

  int opx = y * HW + x;
#pragma unroll
  for (int co = 0; co < 8; co++) {
    int c = cq * 8 + co;
    float val = sacc[co] * bns[c] + bnb[c];
    out[((size_t)(b * CC + c) << 16) + opx] = fmaxf(val, 0.f);
  }
}

extern "C" void kernel_launch(void* const* d_in, const int* in_sizes, int n_in,
                              void* d_out, int out_size, void* d_ws, size_t ws_size,
                              hipStream_t stream) {
  const float* cen = (const float*)d_in[0];
  const float* trans_W = (const float*)d_in[1];
  const float* trans_b = (const float*)d_in[2];
  const float* query_W = (const float*)d_in[3];
  const float* value_W = (const float*)d_in[4];
  const float* key_W = (const float*)d_in[5];
  const float* out_W = (const float*)d_in[6];
  const float* bn_gamma = (const float*)d_in[7];
  const float* bn_beta = (const float*)d_in[8];
  const float* bn_mean = (const float*)d_in[9];
  const float* bn_var = (const float*)d_in[10];
  float* out = (float*)d_out;

  // Buffer plan (race-free, round-7 proven):
  //   kv    = d_out[0, 1048576)    -- fp32 scratch; fully overwritten by k3b.
  //   srraw = ws[0, 6144)
  //   v     = ws[532480, 25698304) -- bf16, channel-last [3][2][65536][32]
  float* kv = (float*)d_out;
  float* srraw = (float*)d_ws;
  __hip_bfloat16* v = (__hip_bfloat16*)((char*)d_ws + 532480);

  k1_trans<<<1024, 256, 0, stream>>>(cen, trans_W, trans_b, kv);
  k23_fat<<<448, 1024, 0, stream>>>(kv, query_W, key_W, srraw, cen, value_W, v);
  k3b_combine<<<2048, 256, 0, stream>>>(v, srraw, out_W, bn_gamma, bn_beta, bn_mean,
                                        bn_var, out);
}

// Round 22
// 161.199 us; speedup vs baseline: 2.1027x; 1.2202x over previous
//
#include <hip/hip_runtime.h>
#include <hip/hip_bf16.h>

// ExpansionContrastModule on MI355X.
// ROUND 22 (= round-20/21 resubmit; both were GPU-acquisition timeouts).
// REVERT to round-9 verbatim (best measured: 160.99us, passed).
// Round-19 evidence closed the channel-last direct-gather k3b family: even with
// per-thread 8-ch chunks, the 27-tap full unroll hoists loads -> VGPR pinned at
// 128 + 155MB scratch writes (3rd spill in this family; dur 70us, total 196.7).
// Pre-committed fallback rule fires: revert to round-9's k3b (vt LDS staging,
// VTS=100 pad) + channel-first K3a. Known-good configuration:
// (1) k1: grid 1024 = b x cog(8) x y, 4 waves = ci-quarters, LDS combine.
// (2) k23_fat: 448 bids, 7-way interleave (3 K2i + 4 K3a) for per-CU balance.
// (3) k3b: grid 512, vt[3*24*VTS] staging with pf prefetch pipeline.
// Buffers (race-free, round-7 proven): kv=d_out[0,1MB) fp32 scratch (fully
// overwritten by k3b), srraw=ws[0,6144), v=ws[532480,25698304) bf16 ch-first.

#define CC 32
#define HW 256
#define KVW 64
#define VTS 100  // vt row stride in floats

// ---------------- K1: 5x5 stride-4 pad-2 conv + bias -> kv [2,32,64,64] ----------------
__global__ __launch_bounds__(256, 2) void k1_trans(const float* __restrict__ cen,
                                                   const float* __restrict__ tW,
                                                   const float* __restrict__ tB,
                                                   float* __restrict__ kv) {
  __shared__ alignas(16) float part[4][4][64];  // [ci-quarter][co][x], 4 KB
  int bid = blockIdx.x;
  int b = bid >> 9, cog = (bid >> 6) & 7, y = bid & 63;
  int tid = threadIdx.x;
  int x = tid & 63;
  int w = __builtin_amdgcn_readfirstlane(tid >> 6);  // wave id 0..3 = ci quarter
  int ci0 = w * 8;
  int co0 = cog * 4;

  float acc[4] = {0.f, 0.f, 0.f, 0.f};
  const float4 z4 = {0.f, 0.f, 0.f, 0.f};

  int roff[5];
  bool rok[5];
#pragma unroll
  for (int r = 0; r < 5; r++) {
    int row = 4 * y - 2 + r;
    rok[r] = (row >= 0);
    roff[r] = (row < 0 ? 0 : row) * HW;
  }

  for (int cc4 = 0; cc4 < 8; cc4 += 4) {
    int ci = ci0 + cc4;
    const float* pc[4];
#pragma unroll
    for (int c = 0; c < 4; c++) pc[c] = cen + (size_t)(b * CC + ci + c) * 65536 + 4 * x;
    float4 A[4][5], B[4][5];
#pragma unroll
    for (int c = 0; c < 4; c++) {
#pragma unroll
      for (int r = 0; r < 5; r++) {
        A[c][r] = (x > 0) ? *(const float4*)(pc[c] + roff[r] - 4) : z4;
        B[c][r] = *(const float4*)(pc[c] + roff[r]);
      }
    }
#pragma unroll
    for (int r = 0; r < 5; r++) {
      if (!rok[r]) continue;  // block-uniform (only y==0, r<2)
#pragma unroll
      for (int c = 0; c < 4; c++) {
#pragma unroll
        for (int co = 0; co < 4; co++) {
          const float* wa = tW + ((co0 + co) * CC + ci + c) * 25 + r * 5;  // s_load
          acc[co] += wa[0] * A[c][r].z + wa[1] * A[c][r].w + wa[2] * B[c][r].x +
                     wa[3] * B[c][r].y + wa[4] * B[c][r].z;
        }
      }
    }
  }

#pragma unroll
  for (int co = 0; co < 4; co++) part[w][co][x] = acc[co];
  __syncthreads();
  {
    int co = tid >> 6, xx = tid & 63;
    float s = part[0][co][xx] + part[1][co][xx] + part[2][co][xx] + part[3][co][xx];
    kv[((b * CC + co0 + co) * KVW + y) * KVW + xx] = s + tB[co0 + co];
  }
}

// ---------------- K23 fat: 448 bids = 64 groups x (3 K2i + 4 K3a) interleaved --------
__device__ inline float wred64(float v) {
#pragma unroll
  for (int off = 1; off < 64; off <<= 1) v += __shfl_xor(v, off);
  return v;
}

__global__ __launch_bounds__(1024) void k23_fat(const float* __restrict__ kv,
                                                const float* __restrict__ qW,
                                                const float* __restrict__ kW,
                                                float* __restrict__ srraw,
                                                const float* __restrict__ cen,
                                                const float* __restrict__ vW,
                                                __hip_bfloat16* __restrict__ v) {
  __shared__ alignas(16) float kl[4096];  // k2i: full 64x64 k_i map (16 KB)
  __shared__ float wredl[16][18];         // k2i: per-wave D[8], M[8], Q2[16]
  int bid = blockIdx.x;
  int tid = threadIdx.x;
  int g = bid / 7, s = bid - g * 7;  // 3 K2i + 4 K3a per group of 7

  if (s < 3) {
    // ---- K2i body: block (bc, i) ----
    int k2id = g * 3 + s;  // 0..191
    int bc = k2id / 3, i = k2id - bc * 3;
    int b = bc >> 5, c = bc & 31;
    int lane = tid & 63, w = tid >> 6;  // w 0..15
    int xx = tid & 63;
    int ybase = tid >> 6;

    float qreg[4];
#pragma unroll
    for (int r = 0; r < 4; r++) {
      int px = r * 1024 + tid;  // row = r*16 + ybase, col = xx
      float q = 0.f, kk = 0.f;
#pragma unroll
      for (int ci = 0; ci < CC; ci++) {
        float val = kv[(b * CC + ci) * 4096 + px];
        q += qW[c * CC + ci] * val;
        kk += kW[(i * CC + c) * CC + ci] * val;
      }
      qreg[r] = q;
      kl[px] = kk;
    }
    __syncthreads();

    float q2 = 0.f;
#pragma unroll
    for (int r = 0; r < 4; r++) q2 += qreg[r] * qreg[r];
    q2 = wred64(q2);
    if (lane == 0) wredl[w][16] = q2;

    constexpr int DYt[8] = {-1, -1, -1, 0, 1, 1, 1, 0};
    constexpr int DXt[8] = {-1, 0, 1, 1, 1, 0, -1, -1};
    const int d = 1 << i;
#pragma unroll
    for (int n = 0; n < 8; n++) {
      const int dy = DYt[n], dx = DXt[n];
      int xn = xx + dx * d;
      bool xok = (xn >= 0 && xn < KVW);
      float dacc = 0.f, macc = 0.f;
#pragma unroll
      for (int r = 0; r < 4; r++) {
        int yy = r * 16 + ybase;
        int px = yy * KVW + xx;
        float kc = kl[px];
        int yn = yy + dy * d;
        float kn = (xok && yn >= 0 && yn < KVW) ? kl[yn * KVW + xn] : 0.f;
        float df = kc - kn;
        dacc += qreg[r] * df;
        macc += df * df;
      }
      dacc = wred64(dacc);
      macc = wred64(macc);
      if (lane == 0) {
        wredl[w][n] = dacc;
        wredl[w][8 + n] = macc;
      }
    }
    __syncthreads();

    // Finalize this block's 8 raw cosine sims (D, M, Q all local; Q bitwise
    // identical across i since qreg and the summation order don't depend on i).
    if (tid < 8) {
      float D = 0.f, M = 0.f, Q = 0.f;
      for (int w2 = 0; w2 < 16; w2++) {
        D += wredl[w2][tid];
        M += wredl[w2][8 + tid];
        Q += wredl[w2][16];
      }
      float sr = D / (fmaxf(sqrtf(M), 1e-12f) * fmaxf(sqrtf(Q), 1e-12f));
      srraw[bc * 24 + i * 8 + tid] = sr;
    }
  } else {
    // ---- K3a body: 4 virtual 256-thread sub-blocks per bid (channel-first v) ----
    int k3id = g * 4 + (s - 3);      // 0..255
    int vb = k3id * 4 + (tid >> 8);  // virtual block 0..1023
    int b = vb >> 9, blk = vb & 511;
    int lane = tid & 63;
    int cg = __builtin_amdgcn_readfirstlane((tid >> 6) & 3);  // wave-uniform c group
    int px = blk * 128 + lane * 2;

    float2 cr[CC];
#pragma unroll
    for (int ci = 0; ci < CC; ci++)
      cr[ci] = *(const float2*)(cen + (size_t)(b * CC + ci) * 65536 + px);

#pragma unroll
    for (int i = 0; i < 3; i++) {
#pragma unroll
      for (int cc = 0; cc < 8; cc++) {
        int c = cg * 8 + cc;
        const float* wp = vW + (i * CC + c) * CC;  // uniform -> s_load
        float a0 = 0.f, a1 = 0.f;
#pragma unroll
        for (int ci = 0; ci < CC; ci++) {
          a0 += wp[ci] * cr[ci].x;
          a1 += wp[ci] * cr[ci].y;
        }
        __hip_bfloat16 h0 = __float2bfloat16(a0);
        __hip_bfloat16 h1 = __float2bfloat16(a1);
        unsigned int pk = (unsigned int)(*(unsigned short*)&h0) |
                          ((unsigned int)(*(unsigned short*)&h1) << 16);
        *(unsigned int*)((unsigned short*)v + (((size_t)((i * 2 + b) * CC + c)) << 16) +
                         px) = pk;
      }
    }
  }
}

// ---------------- K3b: score l2norm + vt-staged combine + out conv + BN + ReLU -------
__global__ __launch_bounds__(256) void k3b_combine(const __hip_bfloat16* __restrict__ v,
                                                   const float* __restrict__ srraw,
                                                   const float* __restrict__ oW,
                                                   const float* __restrict__ gamma,
                                                   const float* __restrict__ beta,
                                                   const float* __restrict__ mean,
                                                   const float* __restrict__ var,
                                                   float* __restrict__ out) {
  __shared__ alignas(16) float vt[3 * 24 * VTS];  // [i][r][col*4+cp], padded stride
  __shared__ alignas(16) float sl[27][32];        // 0..23: s[j][c]; 24..26: S_i[c]
  __shared__ alignas(16) float owl[32][32];       // [co][c]
  __shared__ float bns[32], bnb[32];

  int bid = blockIdx.x;
  int b = bid >> 8, tile = bid & 255;
  int ty = tile >> 4, tx = tile & 15;
  int tid = threadIdx.x;
  int ly = tid >> 4, lx = tid & 15;

  // Raw cosine sims [24 j][32 c] for this b.
  for (int f = tid; f < 768; f += 256) {
    int j = f >> 5, c = f & 31;
    sl[j][c] = srraw[(b * CC + c) * 24 + j];
  }
  for (int f = tid; f < 1024; f += 256) owl[f >> 5][f & 31] = oW[f];
  if (tid < 32) {
    float inv = rsqrtf(var[tid] + 1e-5f);
    float sc = gamma[tid] * inv;
    bns[tid] = sc;
    bnb[tid] = beta[tid] - mean[tid] * sc;
  }
  __syncthreads();
  if (tid < 32) {
    float r2 = 0.f;
#pragma unroll
    for (int j = 0; j < 24; j++) {
      float s = sl[j][tid];
      r2 += s * s;
    }
    float dn = fmaxf(sqrtf(r2), 1e-12f);
#pragma unroll
    for (int j = 0; j < 24; j++) sl[j][tid] /= dn;
#pragma unroll
    for (int i = 0; i < 3; i++) {
      float s = 0.f;
      for (int n = 0; n < 8; n++) s += sl[i * 8 + n][tid];
      sl[24 + i][tid] = s;
    }
  }

  int ldsoff[4], pxoff[4], ibase[4];
  bool okp[4];
#pragma unroll
  for (int it = 0; it < 4; it++) {
    int p = tid + it * 256;
    bool act = (p < 864);
    int pp = act ? p : 0;
    int i = pp / 288;
    int rem = pp - i * 288;
    int r = rem / 12;
    int col = (rem - r * 12) * 2;
    int gy = ty * 16 + r - 4, gx = tx * 16 + col - 4;
    okp[it] = act && gy >= 0 && gy < HW && gx >= 0 && gx < HW;
    pxoff[it] = gy * HW + gx;
    ibase[it] = (i * 2 + b) * CC;
    ldsoff[it] = (i * 24 + r) * VTS + col * 4;  // padded stride
  }

  constexpr int DYt[8] = {-1, -1, -1, 0, 1, 1, 1, 0};
  constexpr int DXt[8] = {-1, 0, 1, 1, 1, 0, -1, -1};

  float acc[32];
#pragma unroll
  for (int co = 0; co < 32; co++) acc[co] = 0.f;

  unsigned int pf[4][4];
  const unsigned short* vs = (const unsigned short*)v;

#pragma unroll
  for (int it = 0; it < 4; it++)
#pragma unroll
    for (int cp = 0; cp < 4; cp++)
      pf[it][cp] = okp[it]
                       ? *(const unsigned int*)(vs + (((size_t)(ibase[it] + cp)) << 16) +
                                                pxoff[it])
                       : 0u;

  for (int cg = 0; cg < 8; cg++) {
    __syncthreads();
#pragma unroll
    for (int it = 0; it < 4; it++) {
      if (it == 3 && tid >= 96) continue;  // p >= 864
      float4 lo, hi;
      lo.x = __uint_as_float(pf[it][0] << 16);
      lo.y = __uint_as_float(pf[it][1] << 16);
      lo.z = __uint_as_float(pf[it][2] << 16);
      lo.w = __uint_as_float(pf[it][3] << 16);
      hi.x = __uint_as_float(pf[it][0] & 0xffff0000u);
      hi.y = __uint_as_float(pf[it][1] & 0xffff0000u);
      hi.z = __uint_as_float(pf[it][2] & 0xffff0000u);
      hi.w = __uint_as_float(pf[it][3] & 0xffff0000u);
      *(float4*)&vt[ldsoff[it]] = lo;
      *(float4*)&vt[ldsoff[it] + 4] = hi;
    }
    if (cg < 7) {
      int cb = (cg + 1) * 4;
#pragma unroll
      for (int it = 0; it < 4; it++)
#pragma unroll
        for (int cp = 0; cp < 4; cp++)
          pf[it][cp] = okp[it] ? *(const unsigned int*)(vs +
                                                        (((size_t)(ibase[it] + cb + cp))
                                                         << 16) +
                                                        pxoff[it])
                               : 0u;
    }
    __syncthreads();

    float4 pre = {0.f, 0.f, 0.f, 0.f};
#pragma unroll
    for (int i = 0; i < 3; i++) {
      const int d = 1 << i;
      float4 S4 = *(const float4*)&sl[24 + i][cg * 4];
      float4 ctr = *(const float4*)&vt[(i * 24 + (ly + 4)) * VTS + (lx + 4) * 4];
      pre.x += S4.x * ctr.x;
      pre.y += S4.y * ctr.y;
      pre.z += S4.z * ctr.z;
      pre.w += S4.w * ctr.w;
#pragma unroll
      for (int n = 0; n < 8; n++) {
        float4 sj = *(const float4*)&sl[i * 8 + n][cg * 4];
        float4 nb = *(const float4*)&vt[(i * 24 + (ly + 4 + DYt[n] * d)) * VTS +
                                        (lx + 4 + DXt[n] * d) * 4];
        pre.x -= sj.x * nb.x;
        pre.y -= sj.y * nb.y;
        pre.z -= sj.z * nb.z;
        pre.w -= sj.w * nb.w;
      }
    }
#pragma unroll
    for (int co = 0; co < 32; co++) {
      float4 ow = *(const float4*)&owl[co][cg * 4];
      acc[co] += ow.x * pre.x + ow.y * pre.y + ow.z * pre.z + ow.w * pre.w;
    }
  }

  int gy = ty * 16 + ly, gx = tx * 16 + lx;
#pragma unroll
  for (int co = 0; co < 32; co++) {
    float val = acc[co] * bns[co] + bnb[co];
    out[((size_t)(b * CC + co) << 16) + gy * HW + gx] = fmaxf(val, 0.f);
  }
}

extern "C" void kernel_launch(void* const* d_in, const int* in_sizes, int n_in,
                              void* d_out, int out_size, void* d_ws, size_t ws_size,
                              hipStream_t stream) {
  const float* cen = (const float*)d_in[0];
  const float* trans_W = (const float*)d_in[1];
  const float* trans_b = (const float*)d_in[2];
  const float* query_W = (const float*)d_in[3];
  const float* value_W = (const float*)d_in[4];
  const float* key_W = (const float*)d_in[5];
  const float* out_W = (const float*)d_in[6];
  const float* bn_gamma = (const float*)d_in[7];
  const float* bn_beta = (const float*)d_in[8];
  const float* bn_mean = (const float*)d_in[9];
  const float* bn_var = (const float*)d_in[10];
  float* out = (float*)d_out;

  // Buffer plan (race-free, round-7 proven):
  //   kv    = d_out[0, 1048576)    -- fp32 scratch; fully overwritten by k3b.
  //   srraw = ws[0, 6144)
  //   v     = ws[532480, 25698304) -- bf16, channel-first [(i*2+b)*CC+c][px]
  float* kv = (float*)d_out;
  float* srraw = (float*)d_ws;
  __hip_bfloat16* v = (__hip_bfloat16*)((char*)d_ws + 532480);

  k1_trans<<<1024, 256, 0, stream>>>(cen, trans_W, trans_b, kv);
  k23_fat<<<448, 1024, 0, stream>>>(kv, query_W, key_W, srraw, cen, value_W, v);
  k3b_combine<<<512, 256, 0, stream>>>(v, srraw, out_W, bn_gamma, bn_beta, bn_mean,
                                       bn_var, out);
}